// Round 1
// baseline (209.367 us; speedup 1.0000x reference)
//
#include <hip/hip_runtime.h>
#include <hip/hip_fp16.h>

#define BATCH 2
#define NCTX  2048
#define WIDTH 1024
#define HEADS 16
#define CH    64
#define QKVD  (3 * WIDTH)
#define MROWS (BATCH * NCTX)

typedef __attribute__((ext_vector_type(4))) float    f32x4;
typedef __attribute__((ext_vector_type(8))) _Float16 f16x8;

// 0.125 (= softmax scale^2) * log2(e), folded into Q so P = exp2(S')
#define QSCALE 0.18033688011112042f

// ---- async global->LDS, 16B per lane. LDS dest = wave-uniform base + lane*16. ----
__device__ __forceinline__ void gll16(void* lds, const void* g) {
    __builtin_amdgcn_global_load_lds(
        (const __attribute__((address_space(1))) unsigned int*)g,
        (__attribute__((address_space(3))) unsigned int*)lds, 16, 0, 0);
}

// pack two f32 -> two f16 (RTZ) as one 32-bit word
__device__ __forceinline__ unsigned pkrtz(float a, float b) {
    auto p = __builtin_amdgcn_cvt_pkrtz(a, b);
    return __builtin_bit_cast(unsigned, p);
}

// ===========================================================================
// split x [4096][1024] f32 -> f16 tiles [mb 32][kt 32][q 4][m 128][8]
// ===========================================================================
__global__ __launch_bounds__(256)
void split_x_f16(const float* __restrict__ x, __half* __restrict__ tiles)
{
    const int mb = blockIdx.x, kt = blockIdx.y;
    const int t = threadIdx.x;
    __half* tb = (__half*)tiles + ((size_t)mb * 32 + kt) * 4096;
    #pragma unroll
    for (int it = 0; it < 2; ++it) {
        const int idx = it * 256 + t;       // 512 cells (m, q)
        const int m = idx >> 2, q = idx & 3;
        const float* src = x + (size_t)(mb * 128 + m) * WIDTH + kt * 32 + q * 8;
        const f32x4 v0 = *(const f32x4*)src;
        const f32x4 v1 = *(const f32x4*)(src + 4);
        f16x8 h;
        #pragma unroll
        for (int j = 0; j < 4; ++j) { h[j] = (_Float16)v0[j]; h[4 + j] = (_Float16)v1[j]; }
        *(f16x8*)&tb[(q * 128 + m) * 8] = h;
    }
}

// ===========================================================================
// split+transpose w [K=1024][N] f32 -> f16 tiles [nb][kt 32][q 4][n 128][8]
// ===========================================================================
__global__ __launch_bounds__(256)
void split_w_f16(const float* __restrict__ w, __half* __restrict__ tiles, int N)
{
    __shared__ float tile[32][129];
    const int nb = blockIdx.x, kt = blockIdx.y;
    const int t = threadIdx.x;
    #pragma unroll
    for (int it = 0; it < 2; ++it) {
        const int idx = it * 256 + t;       // 512 x 8 floats
        const int kk = idx >> 4, n8 = idx & 15;
        const float* src = w + (size_t)(kt * 32 + kk) * N + nb * 128 + n8 * 8;
        #pragma unroll
        for (int j = 0; j < 8; ++j) tile[kk][n8 * 8 + j] = src[j];
    }
    __syncthreads();
    __half* tb = tiles + ((size_t)nb * 32 + kt) * 4096;
    #pragma unroll
    for (int it = 0; it < 2; ++it) {
        const int idx = it * 256 + t;       // 512 cells (q, nn)
        const int q = idx >> 7, nn = idx & 127;
        f16x8 h;
        #pragma unroll
        for (int j = 0; j < 8; ++j) h[j] = (_Float16)tile[q * 8 + j][nn];
        *(f16x8*)&tb[(q * 128 + nn) * 8] = h;
    }
}

// ===========================================================================
// QKV GEMM: 128x128x32 fp16 MFMA, global_load_lds (width 16) double-buffered
// staging, one barrier per K-iter. Epilogue scatters Q (scaled), K, V^T.
// ===========================================================================
__global__ __launch_bounds__(256)
void gemm_qkv(const __half* __restrict__ At, const __half* __restrict__ Bt,
              const float* __restrict__ bias,
              __half* __restrict__ qg, __half* __restrict__ kg, __half* __restrict__ vtg)
{
    __shared__ __align__(16) _Float16 sm[16384];    // 2 buffers x (A 4096 | B 4096)
    const int t = threadIdx.x, lane = t & 63, w = t >> 6;
    const int lq = lane & 15, quad = lane >> 4;
    const int nb = blockIdx.x, mb = blockIdx.y;
    const int wm = (w >> 1) * 64, wn = (w & 1) * 64;

    const __half* Ab = At + ((size_t)mb * 32) * 4096;
    const __half* Bb = Bt + ((size_t)nb * 32) * 4096;
    const int c0 = w * 4;

    f32x4 acc[4][4];
    #pragma unroll
    for (int i = 0; i < 4; ++i)
        #pragma unroll
        for (int j = 0; j < 4; ++j) acc[i][j] = 0;

    // prologue: tile 0 -> buffer 0 (async, drained at the barrier)
    #pragma unroll
    for (int i = 0; i < 4; ++i) {
        const int c = c0 + i;
        const __half* g = (c < 8 ? Ab + c * 512 : Bb + (c - 8) * 512) + lane * 8;
        gll16((void*)&sm[c * 512], (const void*)g);
    }
    __syncthreads();

    for (int kt = 0; kt < 32; ++kt) {
        _Float16* cur = sm + (kt & 1) * 8192;
        _Float16* nxt = sm + ((kt + 1) & 1) * 8192;

        if (kt + 1 < 32) {                  // async stage tile kt+1 into nxt
            #pragma unroll
            for (int i = 0; i < 4; ++i) {
                const int c = c0 + i;
                const __half* g = (c < 8 ? Ab + (size_t)(kt + 1) * 4096 + c * 512
                                         : Bb + (size_t)(kt + 1) * 4096 + (c - 8) * 512) + lane * 8;
                gll16((void*)&nxt[c * 512], (const void*)g);
            }
        }

        f16x8 a[4], b[4];
        #pragma unroll
        for (int i = 0; i < 4; ++i) {
            a[i] = *(const f16x8*)&cur[(quad * 128 + wm + i * 16 + lq) * 8];
            b[i] = *(const f16x8*)&cur[4096 + (quad * 128 + wn + i * 16 + lq) * 8];
        }
        #pragma unroll
        for (int i = 0; i < 4; ++i)
            #pragma unroll
            for (int j = 0; j < 4; ++j)
                acc[i][j] = __builtin_amdgcn_mfma_f32_16x16x32_f16(a[i], b[j], acc[i][j], 0, 0, 0);

        __syncthreads();
    }

    const int bb = mb >> 4;
    #pragma unroll
    for (int jf = 0; jf < 4; ++jf) {
        const int col = nb * 128 + wn + jf * 16 + lq;
        const int h = col / 192;
        const int sect = col - h * 192;
        const int type = sect >> 6;
        const int c = sect & 63;
        const float bv = bias[col];
        const size_t bh = (size_t)bb * 16 + h;
        #pragma unroll
        for (int i = 0; i < 4; ++i) {
            #pragma unroll
            for (int r = 0; r < 4; ++r) {
                const int n = (mb & 15) * 128 + wm + i * 16 + quad * 4 + r;
                const float v = acc[i][jf][r] + bv;
                if (type == 0) {
                    const size_t a2 = ((bh * 16 + (n >> 7)) * 8 + (c >> 3)) * 1024
                                      + (size_t)(n & 127) * 8 + (c & 7);
                    qg[a2] = __float2half(v * QSCALE);
                } else if (type == 1) {
                    const size_t a2 = ((bh * 32 + (n >> 6)) * 8 + (c >> 3)) * 512
                                      + (size_t)(n & 63) * 8 + (c & 7);
                    kg[a2] = __float2half(v);
                } else {
                    const size_t a2 = ((bh * 32 + (n >> 6)) * 8 + ((n >> 3) & 7)) * 512
                                      + (size_t)c * 8 + (n & 7);
                    vtg[a2] = __float2half(v);
                }
            }
        }
    }
}

// ===========================================================================
// Attention v4: 128-q tile per block, no-max softmax (exp2, scale pre-folded),
// PV pipelined one iter behind S^T, l via ones-MFMA, XCD-swizzled bid.
// K/V staged via global_load_lds (async): at iter kt, gll K[kt+1]->Ks[cur^1]
// and V[kt]->Vt[cur]; this iter reads Ks[cur] and Vt[cur^1] -> no overlap.
// LDS: Ks dbuf 16K + Vt dbuf 16K + Ps 32K (Q staging / wave-private P dbuf).
// ===========================================================================
__global__ __launch_bounds__(256)
void attn_mfma3(const __half* __restrict__ qg, const __half* __restrict__ kg,
                const __half* __restrict__ vtg, __half* __restrict__ a2)
{
    __shared__ __align__(16) _Float16 Ks[2][4096];
    __shared__ __align__(16) _Float16 Vt[2][4096];
    __shared__ __align__(16) _Float16 Ps[16384];    // Q staging (first 16KB), then P dbuf

    const int t = threadIdx.x, lane = t & 63, w = t >> 6;
    const int lq = lane & 15, quad = lane >> 4;
    const int bid = blockIdx.x;
    // XCD swizzle: all 16 q-tiles of one (b,h) share bid%8 -> same XCD L2.
    const int qt2 = (bid >> 3) & 15;
    const int bh_ = (bid & 7) + ((bid >> 7) << 3);
    const size_t bh = (size_t)bh_;
    const int h = bh_ & 15, b = bh_ >> 4;

    const __half* qtile = qg + (bh * 16 + qt2) * 8192;
    const __half* kbase = kg + bh * 32 * 4096;
    const __half* vbase = vtg + bh * 32 * 4096;

    // ---- prologue: stage Q and K tile 0 (all async gll16) ----
    #pragma unroll
    for (int i = 0; i < 4; ++i)
        gll16((void*)&Ps[(w * 4 + i) * 512], (const void*)(qtile + (w * 4 + i) * 512 + lane * 8));
    const int lw = w * 1024 + lane * 8;             // this wave's chunk base (halves)
    gll16((void*)&Ks[0][w * 1024],       (const void*)(kbase + lw));
    gll16((void*)&Ks[0][w * 1024 + 512], (const void*)(kbase + lw + 512));
    __syncthreads();                                // Q + K0 staged

    f16x8 aq[2][2];
    #pragma unroll
    for (int qn = 0; qn < 2; ++qn)
        #pragma unroll
        for (int ks = 0; ks < 2; ++ks)
            aq[qn][ks] = *(const f16x8*)&Ps[((ks * 4 + quad) * 128 + w * 32 + qn * 16 + lq) * 8];
    __syncthreads();                                // Ps free for P

    f32x4 O[2][4], Ol[2];
    #pragma unroll
    for (int qn = 0; qn < 2; ++qn) {
        Ol[qn] = 0;
        #pragma unroll
        for (int j = 0; j < 4; ++j) O[qn][j] = 0;
    }
    f16x8 ones;
    #pragma unroll
    for (int j = 0; j < 8; ++j) ones[j] = (_Float16)1.0f;

    _Float16* PwBase = &Ps[w * 4096];               // wave-private, 2 x 2048 halves
    const int kb_hi = quad >> 1, joff = (quad & 1) * 4;
    const f32x4 zc = {0.0f, 0.0f, 0.0f, 0.0f};

    for (int kt = 0; kt < 32; ++kt) {
        const int cur = kt & 1;

        // ---- async staging: K[kt+1] -> Ks[cur^1], V[kt] -> Vt[cur] ----
        if (kt < 31) {
            gll16((void*)&Ks[cur ^ 1][w * 1024],
                  (const void*)(kbase + (size_t)(kt + 1) * 4096 + lw));
            gll16((void*)&Ks[cur ^ 1][w * 1024 + 512],
                  (const void*)(kbase + (size_t)(kt + 1) * 4096 + lw + 512));
        }
        gll16((void*)&Vt[cur][w * 1024],
              (const void*)(vbase + (size_t)kt * 4096 + lw));
        gll16((void*)&Vt[cur][w * 1024 + 512],
              (const void*)(vbase + (size_t)kt * 4096 + lw + 512));

        // ---- S^T(kt): D[key][q], zero-C on first term ----
        f32x4 st[4][2];
        #pragma unroll
        for (int mt = 0; mt < 4; ++mt) {
            f16x8 kf0 = *(const f16x8*)&Ks[cur][((quad) * 64 + mt * 16 + lq) * 8];
            f16x8 kf1 = *(const f16x8*)&Ks[cur][((4 + quad) * 64 + mt * 16 + lq) * 8];
            st[mt][0] = __builtin_amdgcn_mfma_f32_16x16x32_f16(kf0, aq[0][0], zc, 0, 0, 0);
            st[mt][1] = __builtin_amdgcn_mfma_f32_16x16x32_f16(kf0, aq[1][0], zc, 0, 0, 0);
            st[mt][0] = __builtin_amdgcn_mfma_f32_16x16x32_f16(kf1, aq[0][1], st[mt][0], 0, 0, 0);
            st[mt][1] = __builtin_amdgcn_mfma_f32_16x16x32_f16(kf1, aq[1][1], st[mt][1], 0, 0, 0);
        }

        // ---- PV(kt-1): independent of st -> fills the MFMA latency gap ----
        if (kt > 0) {
            const int pv = (kt - 1) & 1;
            _Float16* Pr = PwBase + pv * 2048;
            #pragma unroll
            for (int ks = 0; ks < 2; ++ks) {
                f16x8 ap0 = *(const f16x8*)&Pr[((ks * 4 + quad) * 32 + lq) * 8];
                f16x8 ap1 = *(const f16x8*)&Pr[((ks * 4 + quad) * 32 + 16 + lq) * 8];
                Ol[0] = __builtin_amdgcn_mfma_f32_16x16x32_f16(ap0, ones, Ol[0], 0, 0, 0);
                Ol[1] = __builtin_amdgcn_mfma_f32_16x16x32_f16(ap1, ones, Ol[1], 0, 0, 0);
                #pragma unroll
                for (int jc = 0; jc < 4; ++jc) {
                    f16x8 vf = *(const f16x8*)&Vt[pv][((ks * 4 + quad) * 64 + jc * 16 + lq) * 8];
                    O[0][jc] = __builtin_amdgcn_mfma_f32_16x16x32_f16(ap0, vf, O[0][jc], 0, 0, 0);
                    O[1][jc] = __builtin_amdgcn_mfma_f32_16x16x32_f16(ap1, vf, O[1][jc], 0, 0, 0);
                }
            }
        }

        // ---- P(kt) = exp2(S'), pack fp16, store to wave-private dbuf ----
        {
            _Float16* Pww = PwBase + cur * 2048;
            #pragma unroll
            for (int mt = 0; mt < 4; ++mt) {
                #pragma unroll
                for (int qn = 0; qn < 2; ++qn) {
                    const float e0 = __builtin_amdgcn_exp2f(st[mt][qn][0]);
                    const float e1 = __builtin_amdgcn_exp2f(st[mt][qn][1]);
                    const float e2 = __builtin_amdgcn_exp2f(st[mt][qn][2]);
                    const float e3 = __builtin_amdgcn_exp2f(st[mt][qn][3]);
                    uint2 pk;
                    pk.x = pkrtz(e0, e1);
                    pk.y = pkrtz(e2, e3);
                    *(uint2*)&Pww[((mt * 2 + kb_hi) * 32 + qn * 16 + lq) * 8 + joff] = pk;
                }
            }
        }

        __syncthreads();                // drains gll vmcnt + all DS ops
    }

    // ---- PV(31) ----
    {
        _Float16* Pr = PwBase + 1 * 2048;
        #pragma unroll
        for (int ks = 0; ks < 2; ++ks) {
            f16x8 ap0 = *(const f16x8*)&Pr[((ks * 4 + quad) * 32 + lq) * 8];
            f16x8 ap1 = *(const f16x8*)&Pr[((ks * 4 + quad) * 32 + 16 + lq) * 8];
            Ol[0] = __builtin_amdgcn_mfma_f32_16x16x32_f16(ap0, ones, Ol[0], 0, 0, 0);
            Ol[1] = __builtin_amdgcn_mfma_f32_16x16x32_f16(ap1, ones, Ol[1], 0, 0, 0);
            #pragma unroll
            for (int jc = 0; jc < 4; ++jc) {
                f16x8 vf = *(const f16x8*)&Vt[1][((ks * 4 + quad) * 64 + jc * 16 + lq) * 8];
                O[0][jc] = __builtin_amdgcn_mfma_f32_16x16x32_f16(ap0, vf, O[0][jc], 0, 0, 0);
                O[1][jc] = __builtin_amdgcn_mfma_f32_16x16x32_f16(ap1, vf, O[1][jc], 0, 0, 0);
            }
        }
    }

    // ---- normalize (l from ones-MFMA, per-lane) + store (proj A-tile layout) ----
    float linv[2][4];
    #pragma unroll
    for (int qn = 0; qn < 2; ++qn)
        #pragma unroll
        for (int r = 0; r < 4; ++r)
            linv[qn][r] = 1.0f / Ol[qn][r];

    __half* a2t = a2 + ((size_t)b * 16 + qt2) * 32 * 4096;
    #pragma unroll
    for (int jc = 0; jc < 4; ++jc) {
        const int ch = h * 64 + jc * 16 + lq;
        const int ktp = ch >> 5;
        const int qc = (ch >> 3) & 3;
        const int j = ch & 7;
        #pragma unroll
        for (int qn = 0; qn < 2; ++qn)
            #pragma unroll
            for (int r = 0; r < 4; ++r) {
                const int m = w * 32 + qn * 16 + quad * 4 + r;
                a2t[(size_t)ktp * 4096 + (qc * 128 + m) * 8 + j] =
                    __float2half(O[qn][jc][r] * linv[qn][r]);
            }
    }
}

// ===========================================================================
// Proj GEMM: out = attn @ w_proj + b. global_load_lds staging + double-buffer.
// ===========================================================================
__global__ __launch_bounds__(256)
void gemm_proj(const __half* __restrict__ At, const __half* __restrict__ Bt,
               const float* __restrict__ bias, float* __restrict__ out)
{
    __shared__ __align__(16) _Float16 sm[16384];
    const int t = threadIdx.x, lane = t & 63, w = t >> 6;
    const int lq = lane & 15, quad = lane >> 4;
    const int nb = blockIdx.x, mb = blockIdx.y;
    const int wm = (w >> 1) * 64, wn = (w & 1) * 64;

    const __half* Ab = At + ((size_t)mb * 32) * 4096;
    const __half* Bb = Bt + ((size_t)nb * 32) * 4096;
    const int c0 = w * 4;

    f32x4 acc[4][4];
    #pragma unroll
    for (int i = 0; i < 4; ++i)
        #pragma unroll
        for (int j = 0; j < 4; ++j) acc[i][j] = 0;

    #pragma unroll
    for (int i = 0; i < 4; ++i) {
        const int c = c0 + i;
        const __half* g = (c < 8 ? Ab + c * 512 : Bb + (c - 8) * 512) + lane * 8;
        gll16((void*)&sm[c * 512], (const void*)g);
    }
    __syncthreads();

    for (int kt = 0; kt < 32; ++kt) {
        _Float16* cur = sm + (kt & 1) * 8192;
        _Float16* nxt = sm + ((kt + 1) & 1) * 8192;

        if (kt + 1 < 32) {
            #pragma unroll
            for (int i = 0; i < 4; ++i) {
                const int c = c0 + i;
                const __half* g = (c < 8 ? Ab + (size_t)(kt + 1) * 4096 + c * 512
                                         : Bb + (size_t)(kt + 1) * 4096 + (c - 8) * 512) + lane * 8;
                gll16((void*)&nxt[c * 512], (const void*)g);
            }
        }

        f16x8 a[4], b[4];
        #pragma unroll
        for (int i = 0; i < 4; ++i) {
            a[i] = *(const f16x8*)&cur[(quad * 128 + wm + i * 16 + lq) * 8];
            b[i] = *(const f16x8*)&cur[4096 + (quad * 128 + wn + i * 16 + lq) * 8];
        }
        #pragma unroll
        for (int i = 0; i < 4; ++i)
            #pragma unroll
            for (int j = 0; j < 4; ++j)
                acc[i][j] = __builtin_amdgcn_mfma_f32_16x16x32_f16(a[i], b[j], acc[i][j], 0, 0, 0);

        __syncthreads();
    }

    #pragma unroll
    for (int jf = 0; jf < 4; ++jf) {
        const int col = nb * 128 + wn + jf * 16 + lq;
        const float bv = bias[col];
        #pragma unroll
        for (int i = 0; i < 4; ++i)
            #pragma unroll
            for (int r = 0; r < 4; ++r) {
                const int row = mb * 128 + wm + i * 16 + quad * 4 + r;
                out[(size_t)row * WIDTH + col] = acc[i][jf][r] + bv;
            }
    }
}

// ===========================================================================
extern "C" void kernel_launch(void* const* d_in, const int* in_sizes, int n_in,
                              void* d_out, int out_size, void* d_ws, size_t ws_size,
                              hipStream_t stream)
{
    const float* x      = (const float*)d_in[0];
    const float* w_qkv  = (const float*)d_in[1];
    const float* b_qkv  = (const float*)d_in[2];
    const float* w_proj = (const float*)d_in[3];
    const float* b_proj = (const float*)d_in[4];
    float* out = (float*)d_out;

    char* p = (char*)d_ws;
    size_t o = 0;
    __half* A1  = (__half*)(p + o); o += (size_t)MROWS * WIDTH * 2;
    __half* Bq  = (__half*)(p + o); o += (size_t)WIDTH * QKVD * 2;
    __half* Qg  = (__half*)(p + o); o += (size_t)MROWS * WIDTH * 2;
    __half* Kg  = (__half*)(p + o); o += (size_t)MROWS * WIDTH * 2;
    __half* Vtg = (__half*)(p + o); o += (size_t)MROWS * WIDTH * 2;
    __half* A2  = (__half*)(p + o); o += (size_t)MROWS * WIDTH * 2;
    __half* Bp  = (__half*)(p + o); o += (size_t)WIDTH * WIDTH * 2;

    dim3 blk(256);

    split_x_f16<<<dim3(32, 32), blk, 0, stream>>>(x, A1);
    split_w_f16<<<dim3(24, 32), blk, 0, stream>>>(w_qkv, Bq, QKVD);
    split_w_f16<<<dim3(8, 32),  blk, 0, stream>>>(w_proj, Bp, WIDTH);

    gemm_qkv<<<dim3(24, 32), blk, 0, stream>>>(A1, Bq, b_qkv, Qg, Kg, Vtg);

    attn_mfma3<<<dim3(512), blk, 0, stream>>>(Qg, Kg, Vtg, A2);

    gemm_proj<<<dim3(8, 32), blk, 0, stream>>>(A2, Bp, b_proj, out);
}

// Round 2
// 205.546 us; speedup vs baseline: 1.0186x; 1.0186x over previous
//
#include <hip/hip_runtime.h>
#include <hip/hip_fp16.h>

#define BATCH 2
#define NCTX  2048
#define WIDTH 1024
#define HEADS 16
#define CH    64
#define QKVD  (3 * WIDTH)
#define MROWS (BATCH * NCTX)

typedef __attribute__((ext_vector_type(4))) float    f32x4;
typedef __attribute__((ext_vector_type(8))) _Float16 f16x8;

// 0.125 (= softmax scale^2) * log2(e), folded into Q so P = exp2(S')
#define QSCALE 0.18033688011112042f

// ---- async global->LDS, 16B per lane (one-shot Q staging only). ----
__device__ __forceinline__ void gll16(void* lds, const void* g) {
    __builtin_amdgcn_global_load_lds(
        (const __attribute__((address_space(1))) unsigned int*)g,
        (__attribute__((address_space(3))) unsigned int*)lds, 16, 0, 0);
}

// pack two f32 -> two f16 (RTZ) as one 32-bit word
__device__ __forceinline__ unsigned pkrtz(float a, float b) {
    auto p = __builtin_amdgcn_cvt_pkrtz(a, b);
    return __builtin_bit_cast(unsigned, p);
}

// ===========================================================================
// split x [4096][1024] f32 -> f16 tiles [mb 32][kt 32][q 4][m 128][8]
// ===========================================================================
__global__ __launch_bounds__(256)
void split_x_f16(const float* __restrict__ x, __half* __restrict__ tiles)
{
    const int mb = blockIdx.x, kt = blockIdx.y;
    const int t = threadIdx.x;
    __half* tb = (__half*)tiles + ((size_t)mb * 32 + kt) * 4096;
    #pragma unroll
    for (int it = 0; it < 2; ++it) {
        const int idx = it * 256 + t;       // 512 cells (m, q)
        const int m = idx >> 2, q = idx & 3;
        const float* src = x + (size_t)(mb * 128 + m) * WIDTH + kt * 32 + q * 8;
        const f32x4 v0 = *(const f32x4*)src;
        const f32x4 v1 = *(const f32x4*)(src + 4);
        f16x8 h;
        #pragma unroll
        for (int j = 0; j < 4; ++j) { h[j] = (_Float16)v0[j]; h[4 + j] = (_Float16)v1[j]; }
        *(f16x8*)&tb[(q * 128 + m) * 8] = h;
    }
}

// ===========================================================================
// split+transpose w [K=1024][N] f32 -> f16 tiles [nb][kt 32][q 4][n 128][8]
// ===========================================================================
__global__ __launch_bounds__(256)
void split_w_f16(const float* __restrict__ w, __half* __restrict__ tiles, int N)
{
    __shared__ float tile[32][129];
    const int nb = blockIdx.x, kt = blockIdx.y;
    const int t = threadIdx.x;
    #pragma unroll
    for (int it = 0; it < 2; ++it) {
        const int idx = it * 256 + t;       // 512 x 8 floats
        const int kk = idx >> 4, n8 = idx & 15;
        const float* src = w + (size_t)(kt * 32 + kk) * N + nb * 128 + n8 * 8;
        #pragma unroll
        for (int j = 0; j < 8; ++j) tile[kk][n8 * 8 + j] = src[j];
    }
    __syncthreads();
    __half* tb = tiles + ((size_t)nb * 32 + kt) * 4096;
    #pragma unroll
    for (int it = 0; it < 2; ++it) {
        const int idx = it * 256 + t;       // 512 cells (q, nn)
        const int q = idx >> 7, nn = idx & 127;
        f16x8 h;
        #pragma unroll
        for (int j = 0; j < 8; ++j) h[j] = (_Float16)tile[q * 8 + j][nn];
        *(f16x8*)&tb[(q * 128 + nn) * 8] = h;
    }
}

// ===========================================================================
// QKV GEMM: 128x128x32 fp16 MFMA, register-prefetch + LDS double-buffer,
// one barrier per K-iter. Epilogue scatters Q (scaled by QSCALE), K, V^T.
// (reg-prefetch: measured faster than global_load_lds here — R1 post-mortem)
// ===========================================================================
__global__ __launch_bounds__(256)
void gemm_qkv(const __half* __restrict__ At, const __half* __restrict__ Bt,
              const float* __restrict__ bias,
              __half* __restrict__ qg, __half* __restrict__ kg, __half* __restrict__ vtg)
{
    __shared__ __align__(16) _Float16 sm[16384];    // 2 buffers x (A 4096 | B 4096)
    const int t = threadIdx.x, lane = t & 63, w = t >> 6;
    const int lq = lane & 15, quad = lane >> 4;
    const int nb = blockIdx.x, mb = blockIdx.y;
    const int wm = (w >> 1) * 64, wn = (w & 1) * 64;

    const __half* Ab = At + ((size_t)mb * 32) * 4096;
    const __half* Bb = Bt + ((size_t)nb * 32) * 4096;
    const int c0 = w * 4;

    f32x4 acc[4][4];
    #pragma unroll
    for (int i = 0; i < 4; ++i)
        #pragma unroll
        for (int j = 0; j < 4; ++j) acc[i][j] = 0;

    f16x8 pf[4];
    #pragma unroll
    for (int i = 0; i < 4; ++i) {
        const int c = c0 + i;
        const __half* g = (c < 8 ? Ab + c * 512 : Bb + (c - 8) * 512) + lane * 8;
        pf[i] = *(const f16x8*)g;
    }
    #pragma unroll
    for (int i = 0; i < 4; ++i)
        *(f16x8*)&sm[(c0 + i) * 512 + lane * 8] = pf[i];
    __syncthreads();

    for (int kt = 0; kt < 32; ++kt) {
        _Float16* cur = sm + (kt & 1) * 8192;
        _Float16* nxt = sm + ((kt + 1) & 1) * 8192;

        if (kt + 1 < 32) {
            #pragma unroll
            for (int i = 0; i < 4; ++i) {
                const int c = c0 + i;
                const __half* g = (c < 8 ? Ab + (size_t)(kt + 1) * 4096 + c * 512
                                         : Bb + (size_t)(kt + 1) * 4096 + (c - 8) * 512) + lane * 8;
                pf[i] = *(const f16x8*)g;
            }
        }

        f16x8 a[4], b[4];
        #pragma unroll
        for (int i = 0; i < 4; ++i) {
            a[i] = *(const f16x8*)&cur[(quad * 128 + wm + i * 16 + lq) * 8];
            b[i] = *(const f16x8*)&cur[4096 + (quad * 128 + wn + i * 16 + lq) * 8];
        }
        #pragma unroll
        for (int i = 0; i < 4; ++i)
            #pragma unroll
            for (int j = 0; j < 4; ++j)
                acc[i][j] = __builtin_amdgcn_mfma_f32_16x16x32_f16(a[i], b[j], acc[i][j], 0, 0, 0);

        if (kt + 1 < 32) {
            #pragma unroll
            for (int i = 0; i < 4; ++i)
                *(f16x8*)&nxt[(c0 + i) * 512 + lane * 8] = pf[i];
        }
        __syncthreads();
    }

    const int bb = mb >> 4;
    #pragma unroll
    for (int jf = 0; jf < 4; ++jf) {
        const int col = nb * 128 + wn + jf * 16 + lq;
        const int h = col / 192;
        const int sect = col - h * 192;
        const int type = sect >> 6;
        const int c = sect & 63;
        const float bv = bias[col];
        const size_t bh = (size_t)bb * 16 + h;
        #pragma unroll
        for (int i = 0; i < 4; ++i) {
            #pragma unroll
            for (int r = 0; r < 4; ++r) {
                const int n = (mb & 15) * 128 + wm + i * 16 + quad * 4 + r;
                const float v = acc[i][jf][r] + bv;
                if (type == 0) {
                    const size_t a2 = ((bh * 16 + (n >> 7)) * 8 + (c >> 3)) * 1024
                                      + (size_t)(n & 127) * 8 + (c & 7);
                    qg[a2] = __float2half(v * QSCALE);
                } else if (type == 1) {
                    const size_t a2 = ((bh * 32 + (n >> 6)) * 8 + (c >> 3)) * 512
                                      + (size_t)(n & 63) * 8 + (c & 7);
                    kg[a2] = __float2half(v);
                } else {
                    const size_t a2 = ((bh * 32 + (n >> 6)) * 8 + ((n >> 3) & 7)) * 512
                                      + (size_t)c * 8 + (n & 7);
                    vtg[a2] = __float2half(v);
                }
            }
        }
    }
}

// ===========================================================================
// Attention v5: 64-q tile per block (grid 1024 = 4 blocks/CU), in-iter PV,
// single-buffered wave-private P.  LDS = Ks dbuf 16K + Vt dbuf 16K + P 8K
// = 40960 B -> 4 blocks/CU (vs 2 before).  No-max softmax (exp2, scale
// pre-folded), l via ones-MFMA, XCD-swizzled bid (4 bh per XCD -> 2MB L2).
// ===========================================================================
__global__ __launch_bounds__(256)
void attn_mfma5(const __half* __restrict__ qg, const __half* __restrict__ kg,
                const __half* __restrict__ vtg, __half* __restrict__ a2)
{
    __shared__ __align__(16) _Float16 Ks[2][4096];   // 64 keys x 64 ch per buf
    __shared__ __align__(16) _Float16 Vt[2][4096];
    __shared__ __align__(16) _Float16 Ps[4096];      // Q staging, then 4x1K wave P

    const int t = threadIdx.x, lane = t & 63, w = t >> 6;
    const int lq = lane & 15, quad = lane >> 4;
    const int bid = blockIdx.x;
    // XCD swizzle: bid&7 selects bh mod 8 -> all 32 q-tiles of a bh on one XCD.
    const int qt = (bid >> 3) & 31;                  // 64-row q tile [0,32)
    const int bh_ = (bid & 7) + ((bid >> 8) << 3);
    const size_t bh = (size_t)bh_;
    const int h = bh_ & 15, b = bh_ >> 4;

    // Qg tile layout: [bh*16 + 128-row tile][8 cg][128 q][8 ch]; take 64-row half.
    const __half* qtile = qg + (bh * 16 + (qt >> 1)) * 8192 + (size_t)(qt & 1) * 512;
    const __half* kbase = kg + bh * 32 * 4096;
    const __half* vbase = vtg + bh * 32 * 4096;

    // ---- prologue: stage Q (async, [8 cg][64 q][8]), prefetch K0/V0 to regs ----
    #pragma unroll
    for (int i = 0; i < 2; ++i)
        gll16((void*)&Ps[(w * 2 + i) * 512],
              (const void*)(qtile + (size_t)(w * 2 + i) * 1024 + lane * 8));

    const int lw = w * 1024 + lane * 8;              // this wave's LDS chunk (halves)
    f16x8 kpf[2], vpf[2];
    #pragma unroll
    for (int i = 0; i < 2; ++i) {
        kpf[i] = *(const f16x8*)(kbase + lw + i * 512);
        vpf[i] = *(const f16x8*)(vbase + lw + i * 512);
    }
    __syncthreads();                                 // Q staged

    #pragma unroll
    for (int i = 0; i < 2; ++i) {
        *(f16x8*)&Ks[0][lw + i * 512] = kpf[i];
        *(f16x8*)&Vt[0][lw + i * 512] = vpf[i];
    }
    f16x8 aq[2];                                     // Q B-fragments, wave's 16 q rows
    #pragma unroll
    for (int ks = 0; ks < 2; ++ks)
        aq[ks] = *(const f16x8*)&Ps[((ks * 4 + quad) * 64 + w * 16 + lq) * 8];
    __syncthreads();                                 // buf0 visible; Ps free for P

    f32x4 O[4], Ol;
    Ol = 0;
    #pragma unroll
    for (int j = 0; j < 4; ++j) O[j] = 0;
    f16x8 ones;
    #pragma unroll
    for (int j = 0; j < 8; ++j) ones[j] = (_Float16)1.0f;

    _Float16* Pw = &Ps[w * 1024];                    // wave-private P (64 keys x 16 q)
    const int kb_hi = quad >> 1, joff = (quad & 1) * 4;
    const f32x4 zc = {0.0f, 0.0f, 0.0f, 0.0f};

    const __half* kp = kbase + 4096 + lw;            // tile kt+1 pointers
    const __half* vp = vbase + 4096 + lw;

    for (int kt = 0; kt < 32; ++kt) {
        const int cur = kt & 1;

        if (kt < 31) {                               // issue prefetch loads first
            kpf[0] = *(const f16x8*)(kp);
            kpf[1] = *(const f16x8*)(kp + 512);
            vpf[0] = *(const f16x8*)(vp);
            vpf[1] = *(const f16x8*)(vp + 512);
            kp += 4096; vp += 4096;
        }

        // ---- S^T(kt): D[key 64][q 16] per wave ----
        f32x4 st[4];
        #pragma unroll
        for (int mt = 0; mt < 4; ++mt) {
            f16x8 kf0 = *(const f16x8*)&Ks[cur][((quad) * 64 + mt * 16 + lq) * 8];
            f16x8 kf1 = *(const f16x8*)&Ks[cur][((4 + quad) * 64 + mt * 16 + lq) * 8];
            st[mt] = __builtin_amdgcn_mfma_f32_16x16x32_f16(kf0, aq[0], zc, 0, 0, 0);
            st[mt] = __builtin_amdgcn_mfma_f32_16x16x32_f16(kf1, aq[1], st[mt], 0, 0, 0);
        }

        // ---- P(kt) = exp2(S'), pack fp16, wave-private store ----
        #pragma unroll
        for (int mt = 0; mt < 4; ++mt) {
            const float e0 = __builtin_amdgcn_exp2f(st[mt][0]);
            const float e1 = __builtin_amdgcn_exp2f(st[mt][1]);
            const float e2 = __builtin_amdgcn_exp2f(st[mt][2]);
            const float e3 = __builtin_amdgcn_exp2f(st[mt][3]);
            uint2 pk;
            pk.x = pkrtz(e0, e1);
            pk.y = pkrtz(e2, e3);
            *(uint2*)&Pw[((mt * 2 + kb_hi) * 16 + lq) * 8 + joff] = pk;
        }

        // ---- PV(kt): wave-local P readback (in-order DS pipe), no barrier ----
        #pragma unroll
        for (int ks = 0; ks < 2; ++ks) {
            f16x8 ap = *(const f16x8*)&Pw[((ks * 4 + quad) * 16 + lq) * 8];
            Ol = __builtin_amdgcn_mfma_f32_16x16x32_f16(ap, ones, Ol, 0, 0, 0);
            #pragma unroll
            for (int jc = 0; jc < 4; ++jc) {
                f16x8 vf = *(const f16x8*)&Vt[cur][((ks * 4 + quad) * 64 + jc * 16 + lq) * 8];
                O[jc] = __builtin_amdgcn_mfma_f32_16x16x32_f16(ap, vf, O[jc], 0, 0, 0);
            }
        }

        // ---- stage K/V tile kt+1 into the other buffer ----
        if (kt < 31) {
            *(f16x8*)&Ks[cur ^ 1][lw]       = kpf[0];
            *(f16x8*)&Ks[cur ^ 1][lw + 512] = kpf[1];
            *(f16x8*)&Vt[cur ^ 1][lw]       = vpf[0];
            *(f16x8*)&Vt[cur ^ 1][lw + 512] = vpf[1];
        }
        __syncthreads();
    }

    // ---- normalize (l from ones-MFMA, per-lane) + store (proj A-tile layout) ----
    float linv[4];
    #pragma unroll
    for (int r = 0; r < 4; ++r) linv[r] = 1.0f / Ol[r];

    __half* a2t = a2 + ((size_t)(b * 16 + (qt >> 1)) * 32) * 4096;
    const int mbase = (qt & 1) * 64 + w * 16 + quad * 4;   // row within 128-tile
    #pragma unroll
    for (int jc = 0; jc < 4; ++jc) {
        const int ch = h * 64 + jc * 16 + lq;
        const int ktp = ch >> 5;
        const int qc = (ch >> 3) & 3;
        const int j = ch & 7;
        #pragma unroll
        for (int r = 0; r < 4; ++r) {
            a2t[(size_t)ktp * 4096 + (qc * 128 + mbase + r) * 8 + j] =
                __float2half(O[jc][r] * linv[r]);
        }
    }
}

// ===========================================================================
// Proj GEMM: out = attn @ w_proj + b. Prefetch + double-buffer (reg-staged).
// ===========================================================================
__global__ __launch_bounds__(256)
void gemm_proj(const __half* __restrict__ At, const __half* __restrict__ Bt,
               const float* __restrict__ bias, float* __restrict__ out)
{
    __shared__ __align__(16) _Float16 sm[16384];
    const int t = threadIdx.x, lane = t & 63, w = t >> 6;
    const int lq = lane & 15, quad = lane >> 4;
    const int nb = blockIdx.x, mb = blockIdx.y;
    const int wm = (w >> 1) * 64, wn = (w & 1) * 64;

    const __half* Ab = At + ((size_t)mb * 32) * 4096;
    const __half* Bb = Bt + ((size_t)nb * 32) * 4096;
    const int c0 = w * 4;

    f32x4 acc[4][4];
    #pragma unroll
    for (int i = 0; i < 4; ++i)
        #pragma unroll
        for (int j = 0; j < 4; ++j) acc[i][j] = 0;

    f16x8 pf[4];
    #pragma unroll
    for (int i = 0; i < 4; ++i) {
        const int c = c0 + i;
        const __half* g = (c < 8 ? Ab + c * 512 : Bb + (c - 8) * 512) + lane * 8;
        pf[i] = *(const f16x8*)g;
    }
    #pragma unroll
    for (int i = 0; i < 4; ++i)
        *(f16x8*)&sm[(c0 + i) * 512 + lane * 8] = pf[i];
    __syncthreads();

    for (int kt = 0; kt < 32; ++kt) {
        _Float16* cur = sm + (kt & 1) * 8192;
        _Float16* nxt = sm + ((kt + 1) & 1) * 8192;

        if (kt + 1 < 32) {
            #pragma unroll
            for (int i = 0; i < 4; ++i) {
                const int c = c0 + i;
                const __half* g = (c < 8 ? Ab + (size_t)(kt + 1) * 4096 + c * 512
                                         : Bb + (size_t)(kt + 1) * 4096 + (c - 8) * 512) + lane * 8;
                pf[i] = *(const f16x8*)g;
            }
        }

        f16x8 a[4], b[4];
        #pragma unroll
        for (int i = 0; i < 4; ++i) {
            a[i] = *(const f16x8*)&cur[(quad * 128 + wm + i * 16 + lq) * 8];
            b[i] = *(const f16x8*)&cur[4096 + (quad * 128 + wn + i * 16 + lq) * 8];
        }
        #pragma unroll
        for (int i = 0; i < 4; ++i)
            #pragma unroll
            for (int j = 0; j < 4; ++j)
                acc[i][j] = __builtin_amdgcn_mfma_f32_16x16x32_f16(a[i], b[j], acc[i][j], 0, 0, 0);

        if (kt + 1 < 32) {
            #pragma unroll
            for (int i = 0; i < 4; ++i)
                *(f16x8*)&nxt[(c0 + i) * 512 + lane * 8] = pf[i];
        }
        __syncthreads();
    }

    #pragma unroll
    for (int jf = 0; jf < 4; ++jf) {
        const int col = nb * 128 + wn + jf * 16 + lq;
        const float bv = bias[col];
        #pragma unroll
        for (int i = 0; i < 4; ++i)
            #pragma unroll
            for (int r = 0; r < 4; ++r) {
                const int row = mb * 128 + wm + i * 16 + quad * 4 + r;
                out[(size_t)row * WIDTH + col] = acc[i][jf][r] + bv;
            }
    }
}

// ===========================================================================
extern "C" void kernel_launch(void* const* d_in, const int* in_sizes, int n_in,
                              void* d_out, int out_size, void* d_ws, size_t ws_size,
                              hipStream_t stream)
{
    const float* x      = (const float*)d_in[0];
    const float* w_qkv  = (const float*)d_in[1];
    const float* b_qkv  = (const float*)d_in[2];
    const float* w_proj = (const float*)d_in[3];
    const float* b_proj = (const float*)d_in[4];
    float* out = (float*)d_out;

    char* p = (char*)d_ws;
    size_t o = 0;
    __half* A1  = (__half*)(p + o); o += (size_t)MROWS * WIDTH * 2;
    __half* Bq  = (__half*)(p + o); o += (size_t)WIDTH * QKVD * 2;
    __half* Qg  = (__half*)(p + o); o += (size_t)MROWS * WIDTH * 2;
    __half* Kg  = (__half*)(p + o); o += (size_t)MROWS * WIDTH * 2;
    __half* Vtg = (__half*)(p + o); o += (size_t)MROWS * WIDTH * 2;
    __half* A2  = (__half*)(p + o); o += (size_t)MROWS * WIDTH * 2;
    __half* Bp  = (__half*)(p + o); o += (size_t)WIDTH * WIDTH * 2;

    dim3 blk(256);

    split_x_f16<<<dim3(32, 32), blk, 0, stream>>>(x, A1);
    split_w_f16<<<dim3(24, 32), blk, 0, stream>>>(w_qkv, Bq, QKVD);
    split_w_f16<<<dim3(8, 32),  blk, 0, stream>>>(w_proj, Bp, WIDTH);

    gemm_qkv<<<dim3(24, 32), blk, 0, stream>>>(A1, Bq, b_qkv, Qg, Kg, Vtg);

    attn_mfma5<<<dim3(1024), blk, 0, stream>>>(Qg, Kg, Vtg, A2);

    gemm_proj<<<dim3(8, 32), blk, 0, stream>>>(A2, Bp, b_proj, out);
}

// Round 3
// 204.497 us; speedup vs baseline: 1.0238x; 1.0051x over previous
//
#include <hip/hip_runtime.h>
#include <hip/hip_fp16.h>

#define BATCH 2
#define NCTX  2048
#define WIDTH 1024
#define HEADS 16
#define CH    64
#define QKVD  (3 * WIDTH)
#define MROWS (BATCH * NCTX)

typedef __attribute__((ext_vector_type(4))) float    f32x4;
typedef __attribute__((ext_vector_type(8))) _Float16 f16x8;

// 0.125 (= softmax scale^2) * log2(e), folded into Q so P = exp2(S')
#define QSCALE 0.18033688011112042f

// ---- async global->LDS, 16B per lane (one-shot Q staging only). ----
__device__ __forceinline__ void gll16(void* lds, const void* g) {
    __builtin_amdgcn_global_load_lds(
        (const __attribute__((address_space(1))) unsigned int*)g,
        (__attribute__((address_space(3))) unsigned int*)lds, 16, 0, 0);
}

// pack two f32 -> two f16 (RTZ) as one 32-bit word
__device__ __forceinline__ unsigned pkrtz(float a, float b) {
    auto p = __builtin_amdgcn_cvt_pkrtz(a, b);
    return __builtin_bit_cast(unsigned, p);
}

// ===========================================================================
// split x [4096][1024] f32 -> f16 tiles [mb 32][kt 32][q 4][m 128][8]
// ===========================================================================
__global__ __launch_bounds__(256)
void split_x_f16(const float* __restrict__ x, __half* __restrict__ tiles)
{
    const int mb = blockIdx.x, kt = blockIdx.y;
    const int t = threadIdx.x;
    __half* tb = (__half*)tiles + ((size_t)mb * 32 + kt) * 4096;
    #pragma unroll
    for (int it = 0; it < 2; ++it) {
        const int idx = it * 256 + t;       // 512 cells (m, q)
        const int m = idx >> 2, q = idx & 3;
        const float* src = x + (size_t)(mb * 128 + m) * WIDTH + kt * 32 + q * 8;
        const f32x4 v0 = *(const f32x4*)src;
        const f32x4 v1 = *(const f32x4*)(src + 4);
        f16x8 h;
        #pragma unroll
        for (int j = 0; j < 4; ++j) { h[j] = (_Float16)v0[j]; h[4 + j] = (_Float16)v1[j]; }
        *(f16x8*)&tb[(q * 128 + m) * 8] = h;
    }
}

// ===========================================================================
// split+transpose w [K=1024][N] f32 -> f16 tiles [nb][kt 32][q 4][n 128][8]
// ===========================================================================
__global__ __launch_bounds__(256)
void split_w_f16(const float* __restrict__ w, __half* __restrict__ tiles, int N)
{
    __shared__ float tile[32][129];
    const int nb = blockIdx.x, kt = blockIdx.y;
    const int t = threadIdx.x;
    #pragma unroll
    for (int it = 0; it < 2; ++it) {
        const int idx = it * 256 + t;       // 512 x 8 floats
        const int kk = idx >> 4, n8 = idx & 15;
        const float* src = w + (size_t)(kt * 32 + kk) * N + nb * 128 + n8 * 8;
        #pragma unroll
        for (int j = 0; j < 8; ++j) tile[kk][n8 * 8 + j] = src[j];
    }
    __syncthreads();
    __half* tb = tiles + ((size_t)nb * 32 + kt) * 4096;
    #pragma unroll
    for (int it = 0; it < 2; ++it) {
        const int idx = it * 256 + t;       // 512 cells (q, nn)
        const int q = idx >> 7, nn = idx & 127;
        f16x8 h;
        #pragma unroll
        for (int j = 0; j < 8; ++j) h[j] = (_Float16)tile[q * 8 + j][nn];
        *(f16x8*)&tb[(q * 128 + nn) * 8] = h;
    }
}

// ===========================================================================
// QKV GEMM: 128x128x32 fp16 MFMA, register-prefetch + LDS double-buffer,
// one barrier per K-iter. Epilogue scatters Q (scaled by QSCALE), K, V^T.
// (reg-prefetch: measured faster than global_load_lds here — R1 post-mortem)
// ===========================================================================
__global__ __launch_bounds__(256)
void gemm_qkv(const __half* __restrict__ At, const __half* __restrict__ Bt,
              const float* __restrict__ bias,
              __half* __restrict__ qg, __half* __restrict__ kg, __half* __restrict__ vtg)
{
    __shared__ __align__(16) _Float16 sm[16384];    // 2 buffers x (A 4096 | B 4096)
    const int t = threadIdx.x, lane = t & 63, w = t >> 6;
    const int lq = lane & 15, quad = lane >> 4;
    const int nb = blockIdx.x, mb = blockIdx.y;
    const int wm = (w >> 1) * 64, wn = (w & 1) * 64;

    const __half* Ab = At + ((size_t)mb * 32) * 4096;
    const __half* Bb = Bt + ((size_t)nb * 32) * 4096;
    const int c0 = w * 4;

    f32x4 acc[4][4];
    #pragma unroll
    for (int i = 0; i < 4; ++i)
        #pragma unroll
        for (int j = 0; j < 4; ++j) acc[i][j] = 0;

    f16x8 pf[4];
    #pragma unroll
    for (int i = 0; i < 4; ++i) {
        const int c = c0 + i;
        const __half* g = (c < 8 ? Ab + c * 512 : Bb + (c - 8) * 512) + lane * 8;
        pf[i] = *(const f16x8*)g;
    }
    #pragma unroll
    for (int i = 0; i < 4; ++i)
        *(f16x8*)&sm[(c0 + i) * 512 + lane * 8] = pf[i];
    __syncthreads();

    for (int kt = 0; kt < 32; ++kt) {
        _Float16* cur = sm + (kt & 1) * 8192;
        _Float16* nxt = sm + ((kt + 1) & 1) * 8192;

        if (kt + 1 < 32) {
            #pragma unroll
            for (int i = 0; i < 4; ++i) {
                const int c = c0 + i;
                const __half* g = (c < 8 ? Ab + (size_t)(kt + 1) * 4096 + c * 512
                                         : Bb + (size_t)(kt + 1) * 4096 + (c - 8) * 512) + lane * 8;
                pf[i] = *(const f16x8*)g;
            }
        }

        f16x8 a[4], b[4];
        #pragma unroll
        for (int i = 0; i < 4; ++i) {
            a[i] = *(const f16x8*)&cur[(quad * 128 + wm + i * 16 + lq) * 8];
            b[i] = *(const f16x8*)&cur[4096 + (quad * 128 + wn + i * 16 + lq) * 8];
        }
        #pragma unroll
        for (int i = 0; i < 4; ++i)
            #pragma unroll
            for (int j = 0; j < 4; ++j)
                acc[i][j] = __builtin_amdgcn_mfma_f32_16x16x32_f16(a[i], b[j], acc[i][j], 0, 0, 0);

        if (kt + 1 < 32) {
            #pragma unroll
            for (int i = 0; i < 4; ++i)
                *(f16x8*)&nxt[(c0 + i) * 512 + lane * 8] = pf[i];
        }
        __syncthreads();
    }

    const int bb = mb >> 4;
    #pragma unroll
    for (int jf = 0; jf < 4; ++jf) {
        const int col = nb * 128 + wn + jf * 16 + lq;
        const int h = col / 192;
        const int sect = col - h * 192;
        const int type = sect >> 6;
        const int c = sect & 63;
        const float bv = bias[col];
        const size_t bh = (size_t)bb * 16 + h;
        #pragma unroll
        for (int i = 0; i < 4; ++i) {
            #pragma unroll
            for (int r = 0; r < 4; ++r) {
                const int n = (mb & 15) * 128 + wm + i * 16 + quad * 4 + r;
                const float v = acc[i][jf][r] + bv;
                if (type == 0) {
                    const size_t a2 = ((bh * 16 + (n >> 7)) * 8 + (c >> 3)) * 1024
                                      + (size_t)(n & 127) * 8 + (c & 7);
                    qg[a2] = __float2half(v * QSCALE);
                } else if (type == 1) {
                    const size_t a2 = ((bh * 32 + (n >> 6)) * 8 + (c >> 3)) * 512
                                      + (size_t)(n & 63) * 8 + (c & 7);
                    kg[a2] = __float2half(v);
                } else {
                    const size_t a2 = ((bh * 32 + (n >> 6)) * 8 + ((n >> 3) & 7)) * 512
                                      + (size_t)c * 8 + (n & 7);
                    vtg[a2] = __float2half(v);
                }
            }
        }
    }
}

// ===========================================================================
// Attention v6: 64-q tile (grid 1024, LDS 40960 -> 4 blocks/CU) + PV
// pipelined one iter behind S^T (R0 structure).  At iter kt: S^T(kt) and
// PV(kt-1) are independent MFMA streams; exp2(kt) overlaps PV on the
// VALU/trans pipe.  P single-buffered (wave-private LDS, in-order per wave:
// read P(kt-1) early, write P(kt) later).  V staged one-iter-late via vheld
// so Vt[cur] is written in iter kt and only read in iter kt+1 (barrier-
// separated).  No-max softmax, l via ones-MFMA, XCD-swizzled bid.
// ===========================================================================
__global__ __launch_bounds__(256)
void attn_mfma6(const __half* __restrict__ qg, const __half* __restrict__ kg,
                const __half* __restrict__ vtg, __half* __restrict__ a2)
{
    __shared__ __align__(16) _Float16 Ks[2][4096];   // 64 keys x 64 ch per buf
    __shared__ __align__(16) _Float16 Vt[2][4096];
    __shared__ __align__(16) _Float16 Ps[4096];      // Q staging, then 4x1K wave P

    const int t = threadIdx.x, lane = t & 63, w = t >> 6;
    const int lq = lane & 15, quad = lane >> 4;
    const int bid = blockIdx.x;
    // XCD swizzle: bid&7 selects bh mod 8 -> all 32 q-tiles of a bh on one XCD.
    const int qt = (bid >> 3) & 31;                  // 64-row q tile [0,32)
    const int bh_ = (bid & 7) + ((bid >> 8) << 3);
    const size_t bh = (size_t)bh_;
    const int h = bh_ & 15, b = bh_ >> 4;

    // Qg tile layout: [bh*16 + 128-row tile][8 cg][128 q][8 ch]; take 64-row half.
    const __half* qtile = qg + (bh * 16 + (qt >> 1)) * 8192 + (size_t)(qt & 1) * 512;
    const __half* kbase = kg + bh * 32 * 4096;
    const __half* vbase = vtg + bh * 32 * 4096;

    // ---- prologue: stage Q (async, [8 cg][64 q][8]), prefetch K0/V0 to regs ----
    #pragma unroll
    for (int i = 0; i < 2; ++i)
        gll16((void*)&Ps[(w * 2 + i) * 512],
              (const void*)(qtile + (size_t)(w * 2 + i) * 1024 + lane * 8));

    const int lw = w * 1024 + lane * 8;              // this wave's LDS chunk (halves)
    f16x8 kpf[2], vpf[2], vheld[2];
    #pragma unroll
    for (int i = 0; i < 2; ++i) {
        kpf[i] = *(const f16x8*)(kbase + lw + i * 512);
        vpf[i] = *(const f16x8*)(vbase + lw + i * 512);
    }
    __syncthreads();                                 // Q staged

    #pragma unroll
    for (int i = 0; i < 2; ++i) {
        *(f16x8*)&Ks[0][lw + i * 512] = kpf[i];
        *(f16x8*)&Vt[0][lw + i * 512] = vpf[i];
    }
    f16x8 aq[2];                                     // Q B-fragments, wave's 16 q rows
    #pragma unroll
    for (int ks = 0; ks < 2; ++ks)
        aq[ks] = *(const f16x8*)&Ps[((ks * 4 + quad) * 64 + w * 16 + lq) * 8];
    __syncthreads();                                 // buf0 visible; Ps free for P

    f32x4 O[4], Ol;
    Ol = 0;
    #pragma unroll
    for (int j = 0; j < 4; ++j) O[j] = 0;
    f16x8 ones;
    #pragma unroll
    for (int j = 0; j < 8; ++j) ones[j] = (_Float16)1.0f;

    _Float16* Pw = &Ps[w * 1024];                    // wave-private P (64 keys x 16 q)
    const int kb_hi = quad >> 1, joff = (quad & 1) * 4;
    const f32x4 zc = {0.0f, 0.0f, 0.0f, 0.0f};

    const __half* kp = kbase + 4096 + lw;            // tile kt+1 pointers
    const __half* vp = vbase + 4096 + lw;

    for (int kt = 0; kt < 32; ++kt) {
        const int cur = kt & 1;

        if (kt < 31) {                               // issue prefetch loads first
            kpf[0] = *(const f16x8*)(kp);
            kpf[1] = *(const f16x8*)(kp + 512);
            vpf[0] = *(const f16x8*)(vp);
            vpf[1] = *(const f16x8*)(vp + 512);
            kp += 4096; vp += 4096;
        }

        // ---- S^T(kt): D[key 64][q 16] per wave ----
        f32x4 st[4];
        #pragma unroll
        for (int mt = 0; mt < 4; ++mt) {
            f16x8 kf0 = *(const f16x8*)&Ks[cur][((quad) * 64 + mt * 16 + lq) * 8];
            f16x8 kf1 = *(const f16x8*)&Ks[cur][((4 + quad) * 64 + mt * 16 + lq) * 8];
            st[mt] = __builtin_amdgcn_mfma_f32_16x16x32_f16(kf0, aq[0], zc, 0, 0, 0);
            st[mt] = __builtin_amdgcn_mfma_f32_16x16x32_f16(kf1, aq[1], st[mt], 0, 0, 0);
        }

        // ---- PV(kt-1): reads P(kt-1) (wave-private, in-order DS) and
        //      Vt[cur^1] (= V(kt-1), untouched this iter) -> fills MFMA gap ----
        if (kt > 0) {
            #pragma unroll
            for (int ks = 0; ks < 2; ++ks) {
                f16x8 ap = *(const f16x8*)&Pw[((ks * 4 + quad) * 16 + lq) * 8];
                Ol = __builtin_amdgcn_mfma_f32_16x16x32_f16(ap, ones, Ol, 0, 0, 0);
                #pragma unroll
                for (int jc = 0; jc < 4; ++jc) {
                    f16x8 vf = *(const f16x8*)&Vt[cur ^ 1][((ks * 4 + quad) * 64 + jc * 16 + lq) * 8];
                    O[jc] = __builtin_amdgcn_mfma_f32_16x16x32_f16(ap, vf, O[jc], 0, 0, 0);
                }
            }
        }

        // ---- P(kt) = exp2(S'), pack fp16, wave-private store (after ap reads) ----
        #pragma unroll
        for (int mt = 0; mt < 4; ++mt) {
            const float e0 = __builtin_amdgcn_exp2f(st[mt][0]);
            const float e1 = __builtin_amdgcn_exp2f(st[mt][1]);
            const float e2 = __builtin_amdgcn_exp2f(st[mt][2]);
            const float e3 = __builtin_amdgcn_exp2f(st[mt][3]);
            uint2 pk;
            pk.x = pkrtz(e0, e1);
            pk.y = pkrtz(e2, e3);
            *(uint2*)&Pw[((mt * 2 + kb_hi) * 16 + lq) * 8 + joff] = pk;
        }

        // ---- stage: K(kt+1) -> Ks[cur^1]; V(kt) (held) -> Vt[cur] ----
        if (kt < 31) {
            *(f16x8*)&Ks[cur ^ 1][lw]       = kpf[0];
            *(f16x8*)&Ks[cur ^ 1][lw + 512] = kpf[1];
        }
        if (kt > 0) {
            *(f16x8*)&Vt[cur][lw]       = vheld[0];
            *(f16x8*)&Vt[cur][lw + 512] = vheld[1];
        }
        vheld[0] = vpf[0]; vheld[1] = vpf[1];
        __syncthreads();
    }

    // ---- PV(31): P(31) in Pw, V(31) in Vt[1] (written iter 31, barrier'd) ----
    {
        #pragma unroll
        for (int ks = 0; ks < 2; ++ks) {
            f16x8 ap = *(const f16x8*)&Pw[((ks * 4 + quad) * 16 + lq) * 8];
            Ol = __builtin_amdgcn_mfma_f32_16x16x32_f16(ap, ones, Ol, 0, 0, 0);
            #pragma unroll
            for (int jc = 0; jc < 4; ++jc) {
                f16x8 vf = *(const f16x8*)&Vt[1][((ks * 4 + quad) * 64 + jc * 16 + lq) * 8];
                O[jc] = __builtin_amdgcn_mfma_f32_16x16x32_f16(ap, vf, O[jc], 0, 0, 0);
            }
        }
    }

    // ---- normalize (l from ones-MFMA, per-lane) + store (proj A-tile layout) ----
    float linv[4];
    #pragma unroll
    for (int r = 0; r < 4; ++r) linv[r] = 1.0f / Ol[r];

    __half* a2t = a2 + ((size_t)(b * 16 + (qt >> 1)) * 32) * 4096;
    const int mbase = (qt & 1) * 64 + w * 16 + quad * 4;   // row within 128-tile
    #pragma unroll
    for (int jc = 0; jc < 4; ++jc) {
        const int ch = h * 64 + jc * 16 + lq;
        const int ktp = ch >> 5;
        const int qc = (ch >> 3) & 3;
        const int j = ch & 7;
        #pragma unroll
        for (int r = 0; r < 4; ++r) {
            a2t[(size_t)ktp * 4096 + (qc * 128 + mbase + r) * 8 + j] =
                __float2half(O[jc][r] * linv[r]);
        }
    }
}

// ===========================================================================
// Proj GEMM: out = attn @ w_proj + b. Prefetch + double-buffer (reg-staged).
// ===========================================================================
__global__ __launch_bounds__(256)
void gemm_proj(const __half* __restrict__ At, const __half* __restrict__ Bt,
               const float* __restrict__ bias, float* __restrict__ out)
{
    __shared__ __align__(16) _Float16 sm[16384];
    const int t = threadIdx.x, lane = t & 63, w = t >> 6;
    const int lq = lane & 15, quad = lane >> 4;
    const int nb = blockIdx.x, mb = blockIdx.y;
    const int wm = (w >> 1) * 64, wn = (w & 1) * 64;

    const __half* Ab = At + ((size_t)mb * 32) * 4096;
    const __half* Bb = Bt + ((size_t)nb * 32) * 4096;
    const int c0 = w * 4;

    f32x4 acc[4][4];
    #pragma unroll
    for (int i = 0; i < 4; ++i)
        #pragma unroll
        for (int j = 0; j < 4; ++j) acc[i][j] = 0;

    f16x8 pf[4];
    #pragma unroll
    for (int i = 0; i < 4; ++i) {
        const int c = c0 + i;
        const __half* g = (c < 8 ? Ab + c * 512 : Bb + (c - 8) * 512) + lane * 8;
        pf[i] = *(const f16x8*)g;
    }
    #pragma unroll
    for (int i = 0; i < 4; ++i)
        *(f16x8*)&sm[(c0 + i) * 512 + lane * 8] = pf[i];
    __syncthreads();

    for (int kt = 0; kt < 32; ++kt) {
        _Float16* cur = sm + (kt & 1) * 8192;
        _Float16* nxt = sm + ((kt + 1) & 1) * 8192;

        if (kt + 1 < 32) {
            #pragma unroll
            for (int i = 0; i < 4; ++i) {
                const int c = c0 + i;
                const __half* g = (c < 8 ? Ab + (size_t)(kt + 1) * 4096 + c * 512
                                         : Bb + (size_t)(kt + 1) * 4096 + (c - 8) * 512) + lane * 8;
                pf[i] = *(const f16x8*)g;
            }
        }

        f16x8 a[4], b[4];
        #pragma unroll
        for (int i = 0; i < 4; ++i) {
            a[i] = *(const f16x8*)&cur[(quad * 128 + wm + i * 16 + lq) * 8];
            b[i] = *(const f16x8*)&cur[4096 + (quad * 128 + wn + i * 16 + lq) * 8];
        }
        #pragma unroll
        for (int i = 0; i < 4; ++i)
            #pragma unroll
            for (int j = 0; j < 4; ++j)
                acc[i][j] = __builtin_amdgcn_mfma_f32_16x16x32_f16(a[i], b[j], acc[i][j], 0, 0, 0);

        if (kt + 1 < 32) {
            #pragma unroll
            for (int i = 0; i < 4; ++i)
                *(f16x8*)&nxt[(c0 + i) * 512 + lane * 8] = pf[i];
        }
        __syncthreads();
    }

    #pragma unroll
    for (int jf = 0; jf < 4; ++jf) {
        const int col = nb * 128 + wn + jf * 16 + lq;
        const float bv = bias[col];
        #pragma unroll
        for (int i = 0; i < 4; ++i)
            #pragma unroll
            for (int r = 0; r < 4; ++r) {
                const int row = mb * 128 + wm + i * 16 + quad * 4 + r;
                out[(size_t)row * WIDTH + col] = acc[i][jf][r] + bv;
            }
    }
}

// ===========================================================================
extern "C" void kernel_launch(void* const* d_in, const int* in_sizes, int n_in,
                              void* d_out, int out_size, void* d_ws, size_t ws_size,
                              hipStream_t stream)
{
    const float* x      = (const float*)d_in[0];
    const float* w_qkv  = (const float*)d_in[1];
    const float* b_qkv  = (const float*)d_in[2];
    const float* w_proj = (const float*)d_in[3];
    const float* b_proj = (const float*)d_in[4];
    float* out = (float*)d_out;

    char* p = (char*)d_ws;
    size_t o = 0;
    __half* A1  = (__half*)(p + o); o += (size_t)MROWS * WIDTH * 2;
    __half* Bq  = (__half*)(p + o); o += (size_t)WIDTH * QKVD * 2;
    __half* Qg  = (__half*)(p + o); o += (size_t)MROWS * WIDTH * 2;
    __half* Kg  = (__half*)(p + o); o += (size_t)MROWS * WIDTH * 2;
    __half* Vtg = (__half*)(p + o); o += (size_t)MROWS * WIDTH * 2;
    __half* A2  = (__half*)(p + o); o += (size_t)MROWS * WIDTH * 2;
    __half* Bp  = (__half*)(p + o); o += (size_t)WIDTH * WIDTH * 2;

    dim3 blk(256);

    split_x_f16<<<dim3(32, 32), blk, 0, stream>>>(x, A1);
    split_w_f16<<<dim3(24, 32), blk, 0, stream>>>(w_qkv, Bq, QKVD);
    split_w_f16<<<dim3(8, 32),  blk, 0, stream>>>(w_proj, Bp, WIDTH);

    gemm_qkv<<<dim3(24, 32), blk, 0, stream>>>(A1, Bq, b_qkv, Qg, Kg, Vtg);

    attn_mfma6<<<dim3(1024), blk, 0, stream>>>(Qg, Kg, Vtg, A2);

    gemm_proj<<<dim3(8, 32), blk, 0, stream>>>(A2, Bp, b_proj, out);
}